// Round 15
// baseline (1480.593 us; speedup 1.0000x reference)
//
#include <hip/hip_runtime.h>
#include <hip/hip_bf16.h>
#include <hip/hip_cooperative_groups.h>

namespace cg = cooperative_groups;

#define NN 40000
#define NE 640000
#define NG 2048
#define DD 128
#define NT 10
#define NL 5
#define NB 80  // dst buckets of 512 nodes

typedef __attribute__((ext_vector_type(8))) short short8;
typedef __attribute__((ext_vector_type(8))) float f32x8;
typedef __attribute__((ext_vector_type(4))) float f32x4;
typedef unsigned short ushort_t;
typedef unsigned char uchar_t;

static __device__ __forceinline__ ushort_t f2b(float f) {
    return __bfloat16_as_ushort(__float2bfloat16(f));
}
static __device__ __forceinline__ float b2f(ushort_t u) {
    return __bfloat162float(__ushort_as_bfloat16(u));
}
static __device__ __forceinline__ uchar_t f2p8(float f) {
    return (uchar_t)(__builtin_amdgcn_cvt_pk_fp8_f32(f, 0.f, 0, false) & 0xFF);
}

// One cooperative mega-kernel: zero -> setup -> bucket -> csr ->
// 5x(gather -> mlp) -> poolhead, with grid.sync() between phases.
// All per-phase bodies identical to the verified round-10 kernels.
__global__ void __launch_bounds__(256, 4)
k_mega(const int* __restrict__ xa, const int* __restrict__ ei,
       const int* __restrict__ ea, const int* __restrict__ batch,
       const float* __restrict__ aemb, const float* __restrict__ bemb,
       const float* __restrict__ eps,
       const float* __restrict__ W1, const float* __restrict__ b1,
       const float* __restrict__ g1, const float* __restrict__ bt1,
       const float* __restrict__ m1, const float* __restrict__ v1,
       const float* __restrict__ W2, const float* __restrict__ b2,
       const float* __restrict__ gO, const float* __restrict__ btO,
       const float* __restrict__ mO, const float* __restrict__ vO,
       const float* __restrict__ Wp, const float* __restrict__ bp,
       void* __restrict__ ws, float* __restrict__ out) {
    cg::grid_group gg = cg::this_grid();
    __shared__ __align__(16) char smem[25600];
    const int t = threadIdx.x;
    const int nblk = gridDim.x;

    // workspace layout (identical to round 10)
    ushort_t* x16a = (ushort_t*)ws;
    ushort_t* x16b = x16a + NN * DD;
    ushort_t* h16 = x16b + NN * DD;
    ushort_t* W1P = h16 + NN * DD;
    ushort_t* W2P = W1P + NL * 32768;
    ushort_t* ebsum16 = W2P + NL * 32768;
    uchar_t* x8a = (uchar_t*)(ebsum16 + NL * 65536);
    uchar_t* x8b = x8a + NN * DD;
    int* off = (int*)(x8b + NN * DD);
    int* gcnt = off + 40064;
    int* gbk = gcnt + 80;
    int* epack = gbk + 80;
    int2* ebuf = (int2*)(epack + NE);

    // ---- phase 0: zero gcnt+gbk (160 ints) ----
    if (blockIdx.x == 0 && t < 160) gcnt[t] = 0;
    gg.sync();

    // ---- phase 1: setup (W-pack/ebsum, atom-encode, bucket-count) ----
    for (int u = blockIdx.x; u < 4405; u += nblk) {
        if (u < 1280) {
            int tid = u * 256 + t;
            int layer = tid >> 16;
            int r = tid & 65535;
            int half = r >> 15;
            int q = r & 32767;
            int j = q & 7;
            int lane = (q >> 3) & 63;
            if (half == 0) {
                int kk = (q >> 9) & 3;
                int nt = q >> 11;
                int n = nt * 16 + (lane & 15);
                int k = kk * 32 + (lane >> 4) * 8 + j;
                W1P[layer * 32768 + q] = f2b(W1[(layer * DD + k) * 256 + n]);
            } else {
                int kk = (q >> 9) & 7;
                int nt = q >> 12;
                int n = nt * 16 + (lane & 15);
                int k = kk * 32 + (lane >> 4) * 8 + j;
                W2P[layer * 32768 + q] = f2b(W2[(layer * 256 + k) * DD + n]);
            }
            int d = tid & 127;
            int c = (tid >> 7) & 511;
            const float* bl = bemb + (size_t)layer * 3 * 8 * DD;
            ebsum16[tid] = f2b(bl[(c & 7) * DD + d] + bl[(8 + ((c >> 3) & 7)) * DD + d] +
                               bl[(16 + (c >> 6)) * DD + d]);
        } else if (u < 3780) {
            int bb = u - 1280;
            int* idxS = (int*)smem;  // 144 ints
            if (t < 144) idxS[t] = xa[bb * 144 + t];
            __syncthreads();
            int nl = t >> 4, dcol = t & 15;
            int n = bb * 16 + nl;
            float acc[8];
#pragma unroll
            for (int k = 0; k < 8; ++k) acc[k] = 0.f;
#pragma unroll
            for (int f = 0; f < 9; ++f) {
                const f32x8 v = *(const f32x8*)&aemb[(f * 64 + idxS[nl * 9 + f]) * DD + dcol * 8];
#pragma unroll
                for (int k = 0; k < 8; ++k) acc[k] += v[k];
            }
            short8 o16;
#pragma unroll
            for (int k = 0; k < 8; ++k) o16[k] = (short)f2b(acc[k]);
            *(short8*)&x16a[(size_t)n * DD + dcol * 8] = o16;
            unsigned int lo = 0, hi = 0;
            lo = __builtin_amdgcn_cvt_pk_fp8_f32(acc[0], acc[1], lo, false);
            lo = __builtin_amdgcn_cvt_pk_fp8_f32(acc[2], acc[3], lo, true);
            hi = __builtin_amdgcn_cvt_pk_fp8_f32(acc[4], acc[5], hi, false);
            hi = __builtin_amdgcn_cvt_pk_fp8_f32(acc[6], acc[7], hi, true);
            *(uint2*)&x8a[(size_t)n * DD + dcol * 8] = make_uint2(lo, hi);
        } else {
            int* hist = (int*)smem;  // NB ints
            int e0 = (u - 3780) * 1024;
            if (t < NB) hist[t] = 0;
            __syncthreads();
#pragma unroll
            for (int k = 0; k < 4; ++k) {
                int e = e0 + k * 256 + t;
                atomicAdd(&hist[ei[NE + e] >> 9], 1);
            }
            __syncthreads();
            if (t < NB) atomicAdd(&gcnt[t], hist[t]);
        }
        __syncthreads();
    }
    gg.sync();

    // ---- phase 2: bucket (scan hoisted once per block) ----
    {
        int* hist = (int*)smem;        // NB
        int* sbase = hist + NB;        // NB
        int* sB = sbase + NB;          // 128
        int* exS = sB + 128;           // NB
        int v0 = 0;
        if (t < 128) { v0 = (t < NB) ? gcnt[t] : 0; sB[t] = v0; }
        __syncthreads();
        for (int d = 1; d < 128; d <<= 1) {
            int add = (t < 128 && t >= d) ? sB[t - d] : 0;
            __syncthreads();
            if (t < 128) sB[t] += add;
            __syncthreads();
        }
        if (t < NB) exS[t] = sB[t] - v0;
        __syncthreads();
        for (int u = blockIdx.x; u < NE / 1024; u += nblk) {
            if (t < NB) hist[t] = 0;
            __syncthreads();
            int e0 = u * 1024;
            int rank[4], buck[4], rec[4], dstv[4];
#pragma unroll
            for (int k = 0; k < 4; ++k) {
                int e = e0 + k * 256 + t;
                int src = ei[e];
                int dst = ei[NE + e];
                int a0 = ea[e * 3 + 0], a1 = ea[e * 3 + 1], a2 = ea[e * 3 + 2];
                rec[k] = src | ((a0 | (a1 << 3) | (a2 << 6)) << 16);
                dstv[k] = dst;
                int b = dst >> 9;
                buck[k] = b;
                rank[k] = atomicAdd(&hist[b], 1);
            }
            __syncthreads();
            if (t < NB) sbase[t] = atomicAdd(&gbk[t], hist[t]);
            __syncthreads();
#pragma unroll
            for (int k = 0; k < 4; ++k) {
                int b = buck[k];
                int slot = exS[b] + sbase[b] + rank[k];
                ebuf[slot] = make_int2(rec[k], dstv[k]);
            }
            __syncthreads();
        }
    }
    gg.sync();

    // ---- phase 3: csr (one block per bucket; blocks >= NB idle) ----
    if (blockIdx.x < NB) {
        int b = blockIdx.x;
        int* cnt = (int*)smem;       // 512
        int* cur = cnt + 512;        // 512
        int* sc = cur + 512;         // 256
        int* sB = sc + 256;          // 128
        int v0 = 0;
        if (t < 128) { v0 = (t < NB) ? gcnt[t] : 0; sB[t] = v0; }
        cnt[t] = 0; cnt[t + 256] = 0;
        cur[t] = 0; cur[t + 256] = 0;
        __syncthreads();
        for (int d = 1; d < 128; d <<= 1) {
            int add = (t < 128 && t >= d) ? sB[t - d] : 0;
            __syncthreads();
            if (t < 128) sB[t] += add;
            __syncthreads();
        }
        int base = sB[b] - gcnt[b];
        int end = base + gcnt[b];
        __syncthreads();
        for (int i = base + t; i < end; i += 256)
            atomicAdd(&cnt[ebuf[i].y & 511], 1);
        __syncthreads();
        int a = cnt[2 * t], c2 = cnt[2 * t + 1];
        sc[t] = a + c2;
        __syncthreads();
        for (int d = 1; d < 256; d <<= 1) {
            int add = (t >= d) ? sc[t - d] : 0;
            __syncthreads();
            sc[t] += add;
            __syncthreads();
        }
        int ex = sc[t] - (a + c2);
        cnt[2 * t] = ex;
        cnt[2 * t + 1] = ex + a;
        int n0 = (b << 9) + 2 * t;
        if (n0 <= NN) off[n0] = base + ex;
        if (n0 + 1 <= NN) off[n0 + 1] = base + ex + a;
        __syncthreads();
        for (int i = base + t; i < end; i += 256) {
            int2 s = ebuf[i];
            int l = s.y & 511;
            int r = atomicAdd(&cur[l], 1);
            epack[base + cnt[l] + r] = s.x;
        }
    }
    gg.sync();

    // ---- phase 4: layers ----
    const int lane = t & 63;
    const int halfl = lane >> 5;
    const int q = lane & 31;
    const int wave = t >> 6;
    const int lrow = lane & 15, quad = lane >> 4;

    for (int i = 0; i < NL; ++i) {
        const ushort_t* xin = (i & 1) ? x16b : x16a;
        ushort_t* xout = (i & 1) ? x16a : x16b;
        const uchar_t* x8in = (i & 1) ? x8b : x8a;
        uchar_t* x8out = (i & 1) ? x8a : x8b;
        const ushort_t* ebl = ebsum16 + i * 65536;
        float es = 1.f + eps[i];

        // --- gather (round-10 body, grid-stride) ---
        {
            const ushort4* eb4 = (const ushort4*)ebl;
            const uint* xu = (const uint*)x8in;
            const ushort4* x4 = (const ushort4*)xin;
            for (int u = blockIdx.x; u < NN / 4; u += nblk) {
                int n = u * 4 + wave;
                ushort4 xv = x4[(size_t)n * 32 + q];
                float acc[4];
#pragma unroll
                for (int k = 0; k < 4; ++k) acc[k] = 0.f;
                int p = off[n], p1 = off[n + 1];

                int rec[8], recn[8];
                bool have = (p + 16 <= p1);
                if (have) {
#pragma unroll
                    for (int j = 0; j < 8; ++j) rec[j] = epack[p + 2 * j + halfl];
                }
                while (have) {
                    int np = p + 16;
                    bool nh = (np + 16 <= p1);
                    if (nh) {
#pragma unroll
                        for (int j = 0; j < 8; ++j) recn[j] = epack[np + 2 * j + halfl];
                    }
                    ushort4 vv[8];
                    uint ss[8];
#pragma unroll
                    for (int j = 0; j < 8; ++j) {
                        vv[j] = eb4[(rec[j] >> 16) * 32 + q];
                        ss[j] = xu[(size_t)(rec[j] & 0xFFFF) * 32 + q];
                    }
#pragma unroll
                    for (int j = 0; j < 8; ++j) {
                        acc[0] += fmaxf(b2f(vv[j].x) + __builtin_amdgcn_cvt_f32_fp8((int)ss[j], 0), 0.f);
                        acc[1] += fmaxf(b2f(vv[j].y) + __builtin_amdgcn_cvt_f32_fp8((int)ss[j], 1), 0.f);
                        acc[2] += fmaxf(b2f(vv[j].z) + __builtin_amdgcn_cvt_f32_fp8((int)ss[j], 2), 0.f);
                        acc[3] += fmaxf(b2f(vv[j].w) + __builtin_amdgcn_cvt_f32_fp8((int)ss[j], 3), 0.f);
                    }
                    p = np;
#pragma unroll
                    for (int j = 0; j < 8; ++j) rec[j] = recn[j];
                    have = nh;
                }
                if (p + 8 <= p1) {
                    int r4[4];
#pragma unroll
                    for (int j = 0; j < 4; ++j) r4[j] = epack[p + 2 * j + halfl];
                    ushort4 vv[4];
                    uint ss[4];
#pragma unroll
                    for (int j = 0; j < 4; ++j) {
                        vv[j] = eb4[(r4[j] >> 16) * 32 + q];
                        ss[j] = xu[(size_t)(r4[j] & 0xFFFF) * 32 + q];
                    }
#pragma unroll
                    for (int j = 0; j < 4; ++j) {
                        acc[0] += fmaxf(b2f(vv[j].x) + __builtin_amdgcn_cvt_f32_fp8((int)ss[j], 0), 0.f);
                        acc[1] += fmaxf(b2f(vv[j].y) + __builtin_amdgcn_cvt_f32_fp8((int)ss[j], 1), 0.f);
                        acc[2] += fmaxf(b2f(vv[j].z) + __builtin_amdgcn_cvt_f32_fp8((int)ss[j], 2), 0.f);
                        acc[3] += fmaxf(b2f(vv[j].w) + __builtin_amdgcn_cvt_f32_fp8((int)ss[j], 3), 0.f);
                    }
                    p += 8;
                }
                for (; p < p1; p += 2) {
                    int eA = epack[p];
                    bool hasB = (p + 1 < p1);
                    int eB = hasB ? epack[p + 1] : eA;
                    int r = halfl ? eB : eA;
                    bool valid = halfl ? hasB : true;
                    ushort4 v = eb4[(r >> 16) * 32 + q];
                    uint s = xu[(size_t)(r & 0xFFFF) * 32 + q];
                    if (valid) {
                        acc[0] += fmaxf(b2f(v.x) + __builtin_amdgcn_cvt_f32_fp8((int)s, 0), 0.f);
                        acc[1] += fmaxf(b2f(v.y) + __builtin_amdgcn_cvt_f32_fp8((int)s, 1), 0.f);
                        acc[2] += fmaxf(b2f(v.z) + __builtin_amdgcn_cvt_f32_fp8((int)s, 2), 0.f);
                        acc[3] += fmaxf(b2f(v.w) + __builtin_amdgcn_cvt_f32_fp8((int)s, 3), 0.f);
                    }
                }
#pragma unroll
                for (int k = 0; k < 4; ++k) acc[k] += __shfl_xor(acc[k], 32, 64);
                if (halfl == 0) {
                    ushort4 o;
                    o.x = f2b(acc[0] + es * b2f(xv.x));
                    o.y = f2b(acc[1] + es * b2f(xv.y));
                    o.z = f2b(acc[2] + es * b2f(xv.z));
                    o.w = f2b(acc[3] + es * b2f(xv.w));
                    ((ushort4*)h16)[(size_t)n * 32 + q] = o;
                }
            }
        }
        gg.sync();

        // --- MLP (round-10 body, grid-stride) ---
        {
            const ushort_t* W1Pl = W1P + (size_t)i * 32768;
            const ushort_t* W2Pl = W2P + (size_t)i * 32768;
            const float* b1l = b1 + i * 256;
            const float* g1l = g1 + i * 256;
            const float* bt1l = bt1 + i * 256;
            const float* m1l = m1 + i * 256;
            const float* v1l = v1 + i * 256;
            const float* b2l = b2 + i * DD;
            const float* gOl = gO + i * DD;
            const float* btOl = btO + i * DD;
            const float* mOl = mO + i * DD;
            const float* vOl = vO + i * DD;
            int relu = (i < NL - 1) ? 1 : 0;
            ushort_t* aS = (ushort_t*)smem;            // 32*136
            ushort_t* mid = (ushort_t*)(smem + 8704);  // 32*264

            for (int u = blockIdx.x; u < NN / 32; u += nblk) {
                int row0 = u * 32;
#pragma unroll
                for (int ps = 0; ps < 2; ++ps) {
                    int idx = ps * 256 + t;
                    int r = idx >> 4, c = (idx & 15) * 8;
                    *(short8*)&aS[r * 136 + c] = *(const short8*)&h16[(row0 + r) * DD + c];
                }
                __syncthreads();

                f32x4 acc1[2][4];
#pragma unroll
                for (int rt = 0; rt < 2; ++rt)
#pragma unroll
                    for (int ii = 0; ii < 4; ++ii) acc1[rt][ii] = (f32x4){0.f, 0.f, 0.f, 0.f};
#pragma unroll
                for (int kk = 0; kk < 4; ++kk) {
                    short8 af0 = *(const short8*)&aS[lrow * 136 + kk * 32 + quad * 8];
                    short8 af1 = *(const short8*)&aS[(16 + lrow) * 136 + kk * 32 + quad * 8];
#pragma unroll
                    for (int ii = 0; ii < 4; ++ii) {
                        int nt = wave * 4 + ii;
                        short8 bf = *(const short8*)&W1Pl[((nt * 4 + kk) * 64 + lane) * 8];
                        acc1[0][ii] = __builtin_amdgcn_mfma_f32_16x16x32_bf16(af0, bf, acc1[0][ii], 0, 0, 0);
                        acc1[1][ii] = __builtin_amdgcn_mfma_f32_16x16x32_bf16(af1, bf, acc1[1][ii], 0, 0, 0);
                    }
                }
                __syncthreads();
#pragma unroll
                for (int ii = 0; ii < 4; ++ii) {
                    int col = (wave * 4 + ii) * 16 + lrow;
                    float s1 = g1l[col] * rsqrtf(v1l[col] + 1e-5f);
                    float sh = bt1l[col] - (m1l[col] - b1l[col]) * s1;
#pragma unroll
                    for (int rt = 0; rt < 2; ++rt)
#pragma unroll
                        for (int r = 0; r < 4; ++r) {
                            int row = rt * 16 + quad * 4 + r;
                            float o = acc1[rt][ii][r] * s1 + sh;
                            mid[row * 264 + col] = f2b(fmaxf(o, 0.f));
                        }
                }
                __syncthreads();

                f32x4 acc2[2][2];
#pragma unroll
                for (int rt = 0; rt < 2; ++rt)
#pragma unroll
                    for (int ii = 0; ii < 2; ++ii) acc2[rt][ii] = (f32x4){0.f, 0.f, 0.f, 0.f};
#pragma unroll
                for (int kk = 0; kk < 8; ++kk) {
                    short8 af0 = *(const short8*)&mid[lrow * 264 + kk * 32 + quad * 8];
                    short8 af1 = *(const short8*)&mid[(16 + lrow) * 264 + kk * 32 + quad * 8];
#pragma unroll
                    for (int ii = 0; ii < 2; ++ii) {
                        int nt = wave * 2 + ii;
                        short8 bf = *(const short8*)&W2Pl[((nt * 8 + kk) * 64 + lane) * 8];
                        acc2[0][ii] = __builtin_amdgcn_mfma_f32_16x16x32_bf16(af0, bf, acc2[0][ii], 0, 0, 0);
                        acc2[1][ii] = __builtin_amdgcn_mfma_f32_16x16x32_bf16(af1, bf, acc2[1][ii], 0, 0, 0);
                    }
                }
                uchar_t* s8 = (uchar_t*)aS;
#pragma unroll
                for (int ii = 0; ii < 2; ++ii) {
                    int col = (wave * 2 + ii) * 16 + lrow;
                    float s = gOl[col] * rsqrtf(vOl[col] + 1e-5f);
                    float sh = btOl[col] - (mOl[col] - b2l[col]) * s;
#pragma unroll
                    for (int rt = 0; rt < 2; ++rt)
#pragma unroll
                        for (int r = 0; r < 4; ++r) {
                            int row = rt * 16 + quad * 4 + r;
                            float o = acc2[rt][ii][r] * s + sh;
                            if (relu) o = fmaxf(o, 0.f);
                            xout[(row0 + row) * DD + col] = f2b(o);
                            s8[row * DD + col] = f2p8(o);
                        }
                }
                __syncthreads();
                ((int4*)(x8out + (size_t)row0 * DD))[t] = ((const int4*)s8)[t];
                __syncthreads();
            }
        }
        gg.sync();
    }

    // ---- phase 5: pool + head ----
    {
        float* pp = (float*)smem;        // 4*DD
        float* pfin = pp + 4 * DD;       // DD
        int j = t >> 6, l = t & 63;
        const ushort2* x2 = (const ushort2*)x16b;
        for (int g = blockIdx.x; g < NG; g += nblk) {
            int lo = 0, hi = NN;
            while (lo < hi) { int m = (lo + hi) >> 1; if (batch[m] < g) lo = m + 1; else hi = m; }
            int start = lo;
            hi = NN;
            while (lo < hi) { int m = (lo + hi) >> 1; if (batch[m] < g + 1) lo = m + 1; else hi = m; }
            int end = lo;
            float sx = 0.f, sy = 0.f;
            for (int n = start + j; n < end; n += 4) {
                ushort2 v = x2[(size_t)n * 64 + l];
                sx += b2f(v.x);
                sy += b2f(v.y);
            }
            pp[j * DD + 2 * l] = sx;
            pp[j * DD + 2 * l + 1] = sy;
            __syncthreads();
            if (t < DD) {
                float c = fmaxf((float)(end - start), 1.f);
                pfin[t] = (pp[0 * DD + t] + pp[1 * DD + t] + pp[2 * DD + t] + pp[3 * DD + t]) / c;
            }
            __syncthreads();
            if (t < NT) {
                float acc = bp[t];
#pragma unroll 8
                for (int k = 0; k < DD; ++k) acc = fmaf(pfin[k], Wp[k * NT + t], acc);
                out[g * NT + t] = acc;
            }
            __syncthreads();
        }
    }
}

extern "C" void kernel_launch(void* const* d_in, const int* in_sizes, int n_in,
                              void* d_out, int out_size, void* d_ws, size_t ws_size,
                              hipStream_t stream) {
    const int* x_atom = (const int*)d_in[0];
    const int* edge_index = (const int*)d_in[1];
    const int* edge_attr = (const int*)d_in[2];
    const int* batch = (const int*)d_in[3];
    const float* atom_emb = (const float*)d_in[4];
    const float* bond_emb = (const float*)d_in[5];
    const float* eps = (const float*)d_in[6];
    const float* W1 = (const float*)d_in[7];
    const float* b1 = (const float*)d_in[8];
    const float* g1 = (const float*)d_in[9];
    const float* bt1 = (const float*)d_in[10];
    const float* m1 = (const float*)d_in[11];
    const float* v1 = (const float*)d_in[12];
    const float* W2 = (const float*)d_in[13];
    const float* b2 = (const float*)d_in[14];
    const float* gO = (const float*)d_in[15];
    const float* btO = (const float*)d_in[16];
    const float* mO = (const float*)d_in[17];
    const float* vO = (const float*)d_in[18];
    const float* Wp = (const float*)d_in[19];
    const float* bp = (const float*)d_in[20];
    float* out = (float*)d_out;
    void* ws = d_ws;

    static int grid = 0;
    if (grid == 0) {
        int maxb = 0;
        hipOccupancyMaxActiveBlocksPerMultiprocessor(&maxb, k_mega, 256, 0);
        if (maxb < 1) maxb = 1;
        grid = maxb * 256;
        if (grid > 1536) grid = 1536;
    }

    void* kargs[] = {(void*)&x_atom, (void*)&edge_index, (void*)&edge_attr,
                     (void*)&batch, (void*)&atom_emb, (void*)&bond_emb,
                     (void*)&eps, (void*)&W1, (void*)&b1, (void*)&g1,
                     (void*)&bt1, (void*)&m1, (void*)&v1, (void*)&W2,
                     (void*)&b2, (void*)&gO, (void*)&btO, (void*)&mO,
                     (void*)&vO, (void*)&Wp, (void*)&bp, (void*)&ws,
                     (void*)&out};
    hipLaunchCooperativeKernel((void*)k_mega, dim3(grid), dim3(256), kargs, 0,
                               stream);
}

// Round 16
// 426.575 us; speedup vs baseline: 3.4709x; 3.4709x over previous
//
#include <hip/hip_runtime.h>
#include <hip/hip_bf16.h>

#define NN 40000
#define NE 640000
#define NG 2048
#define DD 128
#define NT 10
#define NL 5
#define NB 80   // dst buckets of 512 nodes
#define NJ 625  // edge blocks of 1024

typedef __attribute__((ext_vector_type(8))) short short8;
typedef __attribute__((ext_vector_type(8))) float f32x8;
typedef __attribute__((ext_vector_type(4))) float f32x4;
typedef unsigned short ushort_t;
typedef unsigned char uchar_t;

static __device__ __forceinline__ ushort_t f2b(float f) {
    return __bfloat16_as_ushort(__float2bfloat16(f));
}
static __device__ __forceinline__ float b2f(ushort_t u) {
    return __bfloat162float(__ushort_as_bfloat16(u));
}
static __device__ __forceinline__ uchar_t f2p8(float f) {
    return (uchar_t)(__builtin_amdgcn_cvt_pk_fp8_f32(f, 0.f, 0, false) & 0xFF);
}

// ------- fused setup: tables + atom-encode + per-block bucket counts -------
// Histogram phase writes pcnt[j][b] NON-atomically (dense) -> no memset and
// no device-scope atomics anywhere in the CSR build.
__global__ void __launch_bounds__(256)
k_setup(const float* __restrict__ W1, const float* __restrict__ W2,
        const float* __restrict__ bemb, const int* __restrict__ xa,
        const float* __restrict__ aemb, const int* __restrict__ ei,
        ushort_t* __restrict__ W1P, ushort_t* __restrict__ W2P,
        ushort_t* __restrict__ ebsum16, ushort_t* __restrict__ x16,
        uchar_t* __restrict__ x8, int* __restrict__ pcnt) {
    int b = blockIdx.x, t = threadIdx.x;
    if (b < 1280) {
        int tid = b * 256 + t;  // < NL*65536
        int layer = tid >> 16;
        int r = tid & 65535;
        int half = r >> 15;
        int q = r & 32767;
        int j = q & 7;
        int lane = (q >> 3) & 63;
        if (half == 0) {
            int kk = (q >> 9) & 3;
            int nt = q >> 11;
            int n = nt * 16 + (lane & 15);
            int k = kk * 32 + (lane >> 4) * 8 + j;
            W1P[layer * 32768 + q] = f2b(W1[(layer * DD + k) * 256 + n]);
        } else {
            int kk = (q >> 9) & 7;
            int nt = q >> 12;
            int n = nt * 16 + (lane & 15);
            int k = kk * 32 + (lane >> 4) * 8 + j;
            W2P[layer * 32768 + q] = f2b(W2[(layer * 256 + k) * DD + n]);
        }
        int d = tid & 127;
        int c = (tid >> 7) & 511;
        const float* bl = bemb + (size_t)layer * 3 * 8 * DD;
        ebsum16[tid] = f2b(bl[(c & 7) * DD + d] + bl[(8 + ((c >> 3) & 7)) * DD + d] +
                           bl[(16 + (c >> 6)) * DD + d]);
    } else if (b < 3780) {
        // atom-encode: 16 nodes/block, thread = (node_local = t>>4, dcol = t&15)
        int bb = b - 1280;
        __shared__ int idxS[144];
        if (t < 144) idxS[t] = xa[bb * 144 + t];
        __syncthreads();
        int nl = t >> 4, dcol = t & 15;
        int n = bb * 16 + nl;
        float acc[8];
#pragma unroll
        for (int k = 0; k < 8; ++k) acc[k] = 0.f;
#pragma unroll
        for (int f = 0; f < 9; ++f) {
            const f32x8 v = *(const f32x8*)&aemb[(f * 64 + idxS[nl * 9 + f]) * DD + dcol * 8];
#pragma unroll
            for (int k = 0; k < 8; ++k) acc[k] += v[k];
        }
        short8 o16;
#pragma unroll
        for (int k = 0; k < 8; ++k) o16[k] = (short)f2b(acc[k]);
        *(short8*)&x16[(size_t)n * DD + dcol * 8] = o16;
        unsigned int lo = 0, hi = 0;
        lo = __builtin_amdgcn_cvt_pk_fp8_f32(acc[0], acc[1], lo, false);
        lo = __builtin_amdgcn_cvt_pk_fp8_f32(acc[2], acc[3], lo, true);
        hi = __builtin_amdgcn_cvt_pk_fp8_f32(acc[4], acc[5], hi, false);
        hi = __builtin_amdgcn_cvt_pk_fp8_f32(acc[6], acc[7], hi, true);
        *(uint2*)&x8[(size_t)n * DD + dcol * 8] = make_uint2(lo, hi);
    } else {
        // bucket count: 1024 edges/block, LDS hist -> dense pcnt row (no atomics)
        __shared__ int hist[NB];
        int j = b - 3780;
        int e0 = j * 1024;
        if (t < NB) hist[t] = 0;
        __syncthreads();
#pragma unroll
        for (int k = 0; k < 4; ++k) {
            int e = e0 + k * 256 + t;
            atomicAdd(&hist[ei[NE + e] >> 9], 1);
        }
        __syncthreads();
        if (t < NB) pcnt[j * NB + t] = hist[t];
    }
}

// Phase A: bin edges by dst bucket into dense runs of ebuf.
// Block j's base in bucket b is DETERMINISTIC: exS[b] + sum_{j'<j} pcnt[j'][b]
// -> zero device-scope atomics.
__global__ void __launch_bounds__(256)
k_bucket(const int* __restrict__ ei, const int* __restrict__ ea,
         const int* __restrict__ pcnt, int2* __restrict__ ebuf) {
    __shared__ int hist[NB];
    __shared__ int pre[NB];
    __shared__ int exS[NB];
    __shared__ int sB[128];
    int t = threadIdx.x;
    int j = blockIdx.x;
    int myT = 0, myP = 0;
    if (t < NB) {
#pragma unroll 5
        for (int jj = 0; jj < NJ; ++jj) {
            int v = pcnt[jj * NB + t];
            myT += v;
            myP += (jj < j) ? v : 0;
        }
        pre[t] = myP;
        hist[t] = 0;
    }
    if (t < 128) sB[t] = (t < NB) ? myT : 0;
    __syncthreads();
    for (int d = 1; d < 128; d <<= 1) {
        int add = (t < 128 && t >= d) ? sB[t - d] : 0;
        __syncthreads();
        if (t < 128) sB[t] += add;
        __syncthreads();
    }
    if (t < NB) exS[t] = sB[t] - myT;
    __syncthreads();
    int e0 = j * 1024;
#pragma unroll
    for (int k = 0; k < 4; ++k) {
        int e = e0 + k * 256 + t;
        int src = ei[e];
        int dst = ei[NE + e];
        int a0 = ea[e * 3 + 0], a1 = ea[e * 3 + 1], a2 = ea[e * 3 + 2];
        int rec = src | ((a0 | (a1 << 3) | (a2 << 6)) << 16);
        int bk = dst >> 9;
        int rank = atomicAdd(&hist[bk], 1);
        ebuf[exS[bk] + pre[bk] + rank] = make_int2(rec, dst);
    }
}

// Per-bucket CSR + scatter: one block per bucket (512 nodes, ~8000 edges).
// All heavy atomics LDS-scope; bucket base/total re-derived from pcnt.
__global__ void __launch_bounds__(256)
k_csr(const int2* __restrict__ ebuf, const int* __restrict__ pcnt,
      int* __restrict__ off, int* __restrict__ epack) {
    __shared__ int cnt[512];
    __shared__ int cur[512];
    __shared__ int sc[256];
    __shared__ int sB[128];
    __shared__ int exS[NB];
    __shared__ int totS[NB];
    int b = blockIdx.x, t = threadIdx.x;
    int myT = 0;
    if (t < NB) {
#pragma unroll 5
        for (int jj = 0; jj < NJ; ++jj) myT += pcnt[jj * NB + t];
        totS[t] = myT;
    }
    if (t < 128) sB[t] = (t < NB) ? myT : 0;
    cnt[t] = 0; cnt[t + 256] = 0;
    cur[t] = 0; cur[t + 256] = 0;
    __syncthreads();
    for (int d = 1; d < 128; d <<= 1) {
        int add = (t < 128 && t >= d) ? sB[t - d] : 0;
        __syncthreads();
        if (t < 128) sB[t] += add;
        __syncthreads();
    }
    if (t < NB) exS[t] = sB[t] - myT;
    __syncthreads();
    int base = exS[b];
    int end = base + totS[b];
    for (int i = base + t; i < end; i += 256)
        atomicAdd(&cnt[ebuf[i].y & 511], 1);
    __syncthreads();
    int a = cnt[2 * t], c2 = cnt[2 * t + 1];
    sc[t] = a + c2;
    __syncthreads();
    for (int d = 1; d < 256; d <<= 1) {
        int add = (t >= d) ? sc[t - d] : 0;
        __syncthreads();
        sc[t] += add;
        __syncthreads();
    }
    int ex = sc[t] - (a + c2);
    cnt[2 * t] = ex;
    cnt[2 * t + 1] = ex + a;
    int n0 = (b << 9) + 2 * t;
    if (n0 <= NN) off[n0] = base + ex;
    if (n0 + 1 <= NN) off[n0 + 1] = base + ex + a;
    __syncthreads();
    for (int i = base + t; i < end; i += 256) {
        int2 s = ebuf[i];
        int l = s.y & 511;
        int r = atomicAdd(&cur[l], 1);
        epack[base + cnt[l] + r] = s.x;
    }
}

// Gather v4 (round-10, unchanged): wave per node; 2 half-waves of 32 lanes,
// each half owns one edge (lane = 4 dims). 16 edges' rows in flight/wave.
__global__ void __launch_bounds__(256)
k_gather(const ushort_t* __restrict__ xin, const uchar_t* __restrict__ x8in,
         const int* __restrict__ off, const int* __restrict__ epack,
         const ushort_t* __restrict__ ebsum16, const float* __restrict__ eps,
         int layer, ushort_t* __restrict__ h16) {
    int t = threadIdx.x;
    int lane = t & 63;
    int half = lane >> 5;
    int q = lane & 31;
    int n = blockIdx.x * 4 + (t >> 6);
    const ushort4* eb4 = (const ushort4*)ebsum16;
    const uint* xu = (const uint*)x8in;
    const ushort4* x4 = (const ushort4*)xin;
    ushort4 xv = x4[(size_t)n * 32 + q];
    float acc[4];
#pragma unroll
    for (int k = 0; k < 4; ++k) acc[k] = 0.f;
    int p = off[n], p1 = off[n + 1];

    int rec[8], recn[8];
    bool have = (p + 16 <= p1);
    if (have) {
#pragma unroll
        for (int j = 0; j < 8; ++j) rec[j] = epack[p + 2 * j + half];
    }
    while (have) {
        int np = p + 16;
        bool nh = (np + 16 <= p1);
        if (nh) {
#pragma unroll
            for (int j = 0; j < 8; ++j) recn[j] = epack[np + 2 * j + half];
        }
        ushort4 vv[8];
        uint ss[8];
#pragma unroll
        for (int j = 0; j < 8; ++j) {
            vv[j] = eb4[(rec[j] >> 16) * 32 + q];
            ss[j] = xu[(size_t)(rec[j] & 0xFFFF) * 32 + q];
        }
#pragma unroll
        for (int j = 0; j < 8; ++j) {
            acc[0] += fmaxf(b2f(vv[j].x) + __builtin_amdgcn_cvt_f32_fp8((int)ss[j], 0), 0.f);
            acc[1] += fmaxf(b2f(vv[j].y) + __builtin_amdgcn_cvt_f32_fp8((int)ss[j], 1), 0.f);
            acc[2] += fmaxf(b2f(vv[j].z) + __builtin_amdgcn_cvt_f32_fp8((int)ss[j], 2), 0.f);
            acc[3] += fmaxf(b2f(vv[j].w) + __builtin_amdgcn_cvt_f32_fp8((int)ss[j], 3), 0.f);
        }
        p = np;
#pragma unroll
        for (int j = 0; j < 8; ++j) rec[j] = recn[j];
        have = nh;
    }
    if (p + 8 <= p1) {
        int r4[4];
#pragma unroll
        for (int j = 0; j < 4; ++j) r4[j] = epack[p + 2 * j + half];
        ushort4 vv[4];
        uint ss[4];
#pragma unroll
        for (int j = 0; j < 4; ++j) {
            vv[j] = eb4[(r4[j] >> 16) * 32 + q];
            ss[j] = xu[(size_t)(r4[j] & 0xFFFF) * 32 + q];
        }
#pragma unroll
        for (int j = 0; j < 4; ++j) {
            acc[0] += fmaxf(b2f(vv[j].x) + __builtin_amdgcn_cvt_f32_fp8((int)ss[j], 0), 0.f);
            acc[1] += fmaxf(b2f(vv[j].y) + __builtin_amdgcn_cvt_f32_fp8((int)ss[j], 1), 0.f);
            acc[2] += fmaxf(b2f(vv[j].z) + __builtin_amdgcn_cvt_f32_fp8((int)ss[j], 2), 0.f);
            acc[3] += fmaxf(b2f(vv[j].w) + __builtin_amdgcn_cvt_f32_fp8((int)ss[j], 3), 0.f);
        }
        p += 8;
    }
    for (; p < p1; p += 2) {
        int eA = epack[p];
        bool hasB = (p + 1 < p1);
        int eB = hasB ? epack[p + 1] : eA;
        int r = half ? eB : eA;
        bool valid = half ? hasB : true;
        ushort4 v = eb4[(r >> 16) * 32 + q];
        uint s = xu[(size_t)(r & 0xFFFF) * 32 + q];
        if (valid) {
            acc[0] += fmaxf(b2f(v.x) + __builtin_amdgcn_cvt_f32_fp8((int)s, 0), 0.f);
            acc[1] += fmaxf(b2f(v.y) + __builtin_amdgcn_cvt_f32_fp8((int)s, 1), 0.f);
            acc[2] += fmaxf(b2f(v.z) + __builtin_amdgcn_cvt_f32_fp8((int)s, 2), 0.f);
            acc[3] += fmaxf(b2f(v.w) + __builtin_amdgcn_cvt_f32_fp8((int)s, 3), 0.f);
        }
    }
#pragma unroll
    for (int k = 0; k < 4; ++k) acc[k] += __shfl_xor(acc[k], 32, 64);
    if (half == 0) {
        float es = 1.f + eps[layer];
        ushort4 o;
        o.x = f2b(acc[0] + es * b2f(xv.x));
        o.y = f2b(acc[1] + es * b2f(xv.y));
        o.z = f2b(acc[2] + es * b2f(xv.z));
        o.w = f2b(acc[3] + es * b2f(xv.w));
        ((ushort4*)h16)[(size_t)n * 32 + q] = o;
    }
}

// Fused MLP on MFMA: 32 nodes per block (round-10 config), 256 threads.
__global__ void __launch_bounds__(256)
k_mlp_mfma(const ushort_t* __restrict__ h16, const ushort_t* __restrict__ W1P,
           const ushort_t* __restrict__ W2P, const float* __restrict__ b1,
           const float* __restrict__ g1, const float* __restrict__ bt1,
           const float* __restrict__ m1, const float* __restrict__ v1,
           const float* __restrict__ b2_, const float* __restrict__ gO,
           const float* __restrict__ btO, const float* __restrict__ mO,
           const float* __restrict__ vO, int relu, ushort_t* __restrict__ xout,
           uchar_t* __restrict__ x8out) {
    __shared__ ushort_t aS[32 * 136];   // 32 rows x 128 (pad +8); reused as fp8 stage
    __shared__ ushort_t mid[32 * 264];  // 32 rows x 256 (pad +8)
    int t = threadIdx.x;
    int wave = t >> 6, lane = t & 63;
    int row0 = blockIdx.x * 32;
    int lrow = lane & 15, quad = lane >> 4;

#pragma unroll
    for (int ps = 0; ps < 2; ++ps) {
        int idx = ps * 256 + t;
        int r = idx >> 4, c = (idx & 15) * 8;
        *(short8*)&aS[r * 136 + c] = *(const short8*)&h16[(row0 + r) * DD + c];
    }
    __syncthreads();

    f32x4 acc1[2][4];
#pragma unroll
    for (int rt = 0; rt < 2; ++rt)
#pragma unroll
        for (int i = 0; i < 4; ++i) acc1[rt][i] = (f32x4){0.f, 0.f, 0.f, 0.f};
#pragma unroll
    for (int kk = 0; kk < 4; ++kk) {
        short8 af0 = *(const short8*)&aS[lrow * 136 + kk * 32 + quad * 8];
        short8 af1 = *(const short8*)&aS[(16 + lrow) * 136 + kk * 32 + quad * 8];
#pragma unroll
        for (int i = 0; i < 4; ++i) {
            int nt = wave * 4 + i;
            short8 bf = *(const short8*)&W1P[((nt * 4 + kk) * 64 + lane) * 8];
            acc1[0][i] = __builtin_amdgcn_mfma_f32_16x16x32_bf16(af0, bf, acc1[0][i], 0, 0, 0);
            acc1[1][i] = __builtin_amdgcn_mfma_f32_16x16x32_bf16(af1, bf, acc1[1][i], 0, 0, 0);
        }
    }
    __syncthreads();  // aS reads done; safe to reuse as fp8 stage
#pragma unroll
    for (int i = 0; i < 4; ++i) {
        int col = (wave * 4 + i) * 16 + lrow;
        float s1 = g1[col] * rsqrtf(v1[col] + 1e-5f);
        float sh = bt1[col] - (m1[col] - b1[col]) * s1;
#pragma unroll
        for (int rt = 0; rt < 2; ++rt)
#pragma unroll
            for (int r = 0; r < 4; ++r) {
                int row = rt * 16 + quad * 4 + r;
                float o = acc1[rt][i][r] * s1 + sh;
                mid[row * 264 + col] = f2b(fmaxf(o, 0.f));
            }
    }
    __syncthreads();

    f32x4 acc2[2][2];
#pragma unroll
    for (int rt = 0; rt < 2; ++rt)
#pragma unroll
        for (int i = 0; i < 2; ++i) acc2[rt][i] = (f32x4){0.f, 0.f, 0.f, 0.f};
#pragma unroll
    for (int kk = 0; kk < 8; ++kk) {
        short8 af0 = *(const short8*)&mid[lrow * 264 + kk * 32 + quad * 8];
        short8 af1 = *(const short8*)&mid[(16 + lrow) * 264 + kk * 32 + quad * 8];
#pragma unroll
        for (int i = 0; i < 2; ++i) {
            int nt = wave * 2 + i;
            short8 bf = *(const short8*)&W2P[((nt * 8 + kk) * 64 + lane) * 8];
            acc2[0][i] = __builtin_amdgcn_mfma_f32_16x16x32_bf16(af0, bf, acc2[0][i], 0, 0, 0);
            acc2[1][i] = __builtin_amdgcn_mfma_f32_16x16x32_bf16(af1, bf, acc2[1][i], 0, 0, 0);
        }
    }
    uchar_t* s8 = (uchar_t*)aS;  // 32*128 = 4096 B stage
#pragma unroll
    for (int i = 0; i < 2; ++i) {
        int col = (wave * 2 + i) * 16 + lrow;
        float s = gO[col] * rsqrtf(vO[col] + 1e-5f);
        float sh = btO[col] - (mO[col] - b2_[col]) * s;
#pragma unroll
        for (int rt = 0; rt < 2; ++rt)
#pragma unroll
            for (int r = 0; r < 4; ++r) {
                int row = rt * 16 + quad * 4 + r;
                float o = acc2[rt][i][r] * s + sh;
                if (relu) o = fmaxf(o, 0.f);
                xout[(row0 + row) * DD + col] = f2b(o);
                s8[row * DD + col] = f2p8(o);
            }
    }
    __syncthreads();
    ((int4*)(x8out + (size_t)row0 * DD))[t] = ((const int4*)s8)[t];
}

// Fused pool+head: 256 threads = 4 row-stripes x 64 dim-pairs (ushort2).
__global__ void k_poolhead(const ushort_t* __restrict__ x16,
                           const int* __restrict__ batch,
                           const float* __restrict__ Wp, const float* __restrict__ bp,
                           float* __restrict__ out) {
    int g = blockIdx.x, t = threadIdx.x;  // 256 threads
    int j = t >> 6, l = t & 63;
    int lo = 0, hi = NN;
    while (lo < hi) { int m = (lo + hi) >> 1; if (batch[m] < g) lo = m + 1; else hi = m; }
    int start = lo;
    hi = NN;
    while (lo < hi) { int m = (lo + hi) >> 1; if (batch[m] < g + 1) lo = m + 1; else hi = m; }
    int end = lo;
    const ushort2* x2 = (const ushort2*)x16;
    float sx = 0.f, sy = 0.f;
    for (int n = start + j; n < end; n += 4) {
        ushort2 v = x2[(size_t)n * 64 + l];
        sx += b2f(v.x);
        sy += b2f(v.y);
    }
    __shared__ float pp[4][DD];
    pp[j][2 * l] = sx;
    pp[j][2 * l + 1] = sy;
    __syncthreads();
    __shared__ float pfin[DD];
    if (t < DD) {
        float c = fmaxf((float)(end - start), 1.f);
        pfin[t] = (pp[0][t] + pp[1][t] + pp[2][t] + pp[3][t]) / c;
    }
    __syncthreads();
    if (t < NT) {
        float acc = bp[t];
#pragma unroll 8
        for (int k = 0; k < DD; ++k) acc = fmaf(pfin[k], Wp[k * NT + t], acc);
        out[g * NT + t] = acc;
    }
}

extern "C" void kernel_launch(void* const* d_in, const int* in_sizes, int n_in,
                              void* d_out, int out_size, void* d_ws, size_t ws_size,
                              hipStream_t stream) {
    const int* x_atom = (const int*)d_in[0];
    const int* edge_index = (const int*)d_in[1];
    const int* edge_attr = (const int*)d_in[2];
    const int* batch = (const int*)d_in[3];
    const float* atom_emb = (const float*)d_in[4];
    const float* bond_emb = (const float*)d_in[5];
    const float* eps = (const float*)d_in[6];
    const float* W1 = (const float*)d_in[7];
    const float* b1 = (const float*)d_in[8];
    const float* g1 = (const float*)d_in[9];
    const float* bt1 = (const float*)d_in[10];
    const float* m1 = (const float*)d_in[11];
    const float* v1 = (const float*)d_in[12];
    const float* W2 = (const float*)d_in[13];
    const float* b2 = (const float*)d_in[14];
    const float* gO = (const float*)d_in[15];
    const float* btO = (const float*)d_in[16];
    const float* mO = (const float*)d_in[17];
    const float* vO = (const float*)d_in[18];
    const float* Wp = (const float*)d_in[19];
    const float* bp = (const float*)d_in[20];

    ushort_t* x16a = (ushort_t*)d_ws;        // N*D bf16
    ushort_t* x16b = x16a + NN * DD;         // N*D bf16
    ushort_t* h16 = x16b + NN * DD;          // N*D bf16
    ushort_t* W1P = h16 + NN * DD;           // NL*32768 bf16
    ushort_t* W2P = W1P + NL * 32768;        // NL*32768 bf16
    ushort_t* ebsum16 = W2P + NL * 32768;    // NL*512*128 bf16
    uchar_t* x8a = (uchar_t*)(ebsum16 + NL * 65536);  // N*D fp8
    uchar_t* x8b = x8a + NN * DD;            // N*D fp8
    int* off = (int*)(x8b + NN * DD);        // 40064
    int* pcnt = off + 40064;                 // NJ*NB = 50000 per-block counts
    int* epack = pcnt + 50048;               // NE int (packed src|code<<16)
    int2* ebuf = (int2*)(epack + NE);        // NE int2

    k_setup<<<4405, 256, 0, stream>>>(W1, W2, bond_emb, x_atom, atom_emb,
                                      edge_index, W1P, W2P, ebsum16, x16a, x8a, pcnt);
    k_bucket<<<NJ, 256, 0, stream>>>(edge_index, edge_attr, pcnt, ebuf);
    k_csr<<<NB, 256, 0, stream>>>(ebuf, pcnt, off, epack);

    for (int i = 0; i < NL; ++i) {
        ushort_t* xin = (i & 1) ? x16b : x16a;
        ushort_t* xout = (i & 1) ? x16a : x16b;
        uchar_t* x8in = (i & 1) ? x8b : x8a;
        uchar_t* x8out = (i & 1) ? x8a : x8b;
        k_gather<<<NN / 4, 256, 0, stream>>>(xin, x8in, off, epack,
                                             ebsum16 + i * 65536, eps, i, h16);
        k_mlp_mfma<<<NN / 32, 256, 0, stream>>>(
            h16, W1P + (size_t)i * 32768, W2P + (size_t)i * 32768, b1 + i * 256,
            g1 + i * 256, bt1 + i * 256, m1 + i * 256, v1 + i * 256, b2 + i * DD,
            gO + i * DD, btO + i * DD, mO + i * DD, vO + i * DD,
            (i < NL - 1) ? 1 : 0, xout, x8out);
    }
    k_poolhead<<<NG, 256, 0, stream>>>(x16b, batch, Wp, bp, (float*)d_out);
}

// Round 17
// 382.895 us; speedup vs baseline: 3.8668x; 1.1141x over previous
//
#include <hip/hip_runtime.h>
#include <hip/hip_bf16.h>

#define NN 40000
#define NE 640000
#define NG 2048
#define DD 128
#define NT 10
#define NL 5
#define NB 80  // dst buckets of 512 nodes

typedef __attribute__((ext_vector_type(8))) short short8;
typedef __attribute__((ext_vector_type(8))) float f32x8;
typedef __attribute__((ext_vector_type(4))) float f32x4;
typedef unsigned short ushort_t;
typedef unsigned char uchar_t;

static __device__ __forceinline__ ushort_t f2b(float f) {
    return __bfloat16_as_ushort(__float2bfloat16(f));
}
static __device__ __forceinline__ float b2f(ushort_t u) {
    return __bfloat162float(__ushort_as_bfloat16(u));
}
static __device__ __forceinline__ uchar_t f2p8(float f) {
    return (uchar_t)(__builtin_amdgcn_cvt_pk_fp8_f32(f, 0.f, 0, false) & 0xFF);
}

// ------- fused setup: tables + atom-encode + BUCKET count (80 bins) --------
__global__ void __launch_bounds__(256)
k_setup(const float* __restrict__ W1, const float* __restrict__ W2,
        const float* __restrict__ bemb, const int* __restrict__ xa,
        const float* __restrict__ aemb, const int* __restrict__ ei,
        ushort_t* __restrict__ W1P, ushort_t* __restrict__ W2P,
        ushort_t* __restrict__ ebsum16, ushort_t* __restrict__ x16,
        uchar_t* __restrict__ x8, int* __restrict__ gcnt) {
    int b = blockIdx.x, t = threadIdx.x;
    if (b < 1280) {
        int tid = b * 256 + t;  // < NL*65536
        int layer = tid >> 16;
        int r = tid & 65535;
        int half = r >> 15;
        int q = r & 32767;
        int j = q & 7;
        int lane = (q >> 3) & 63;
        if (half == 0) {
            int kk = (q >> 9) & 3;
            int nt = q >> 11;
            int n = nt * 16 + (lane & 15);
            int k = kk * 32 + (lane >> 4) * 8 + j;
            W1P[layer * 32768 + q] = f2b(W1[(layer * DD + k) * 256 + n]);
        } else {
            int kk = (q >> 9) & 7;
            int nt = q >> 12;
            int n = nt * 16 + (lane & 15);
            int k = kk * 32 + (lane >> 4) * 8 + j;
            W2P[layer * 32768 + q] = f2b(W2[(layer * 256 + k) * DD + n]);
        }
        int d = tid & 127;
        int c = (tid >> 7) & 511;
        const float* bl = bemb + (size_t)layer * 3 * 8 * DD;
        ebsum16[tid] = f2b(bl[(c & 7) * DD + d] + bl[(8 + ((c >> 3) & 7)) * DD + d] +
                           bl[(16 + (c >> 6)) * DD + d]);
    } else if (b < 3780) {
        // atom-encode: 16 nodes/block, thread = (node_local = t>>4, dcol = t&15)
        int bb = b - 1280;
        __shared__ int idxS[144];
        if (t < 144) idxS[t] = xa[bb * 144 + t];
        __syncthreads();
        int nl = t >> 4, dcol = t & 15;
        int n = bb * 16 + nl;
        float acc[8];
#pragma unroll
        for (int k = 0; k < 8; ++k) acc[k] = 0.f;
#pragma unroll
        for (int f = 0; f < 9; ++f) {
            const f32x8 v = *(const f32x8*)&aemb[(f * 64 + idxS[nl * 9 + f]) * DD + dcol * 8];
#pragma unroll
            for (int k = 0; k < 8; ++k) acc[k] += v[k];
        }
        short8 o16;
#pragma unroll
        for (int k = 0; k < 8; ++k) o16[k] = (short)f2b(acc[k]);
        *(short8*)&x16[(size_t)n * DD + dcol * 8] = o16;
        unsigned int lo = 0, hi = 0;
        lo = __builtin_amdgcn_cvt_pk_fp8_f32(acc[0], acc[1], lo, false);
        lo = __builtin_amdgcn_cvt_pk_fp8_f32(acc[2], acc[3], lo, true);
        hi = __builtin_amdgcn_cvt_pk_fp8_f32(acc[4], acc[5], hi, false);
        hi = __builtin_amdgcn_cvt_pk_fp8_f32(acc[6], acc[7], hi, true);
        *(uint2*)&x8[(size_t)n * DD + dcol * 8] = make_uint2(lo, hi);
    } else {
        // bucket count: 1024 edges/block, LDS hist of 80 bins
        __shared__ int hist[NB];
        int e0 = (b - 3780) * 1024;
        if (t < NB) hist[t] = 0;
        __syncthreads();
#pragma unroll
        for (int k = 0; k < 4; ++k) {
            int e = e0 + k * 256 + t;
            atomicAdd(&hist[ei[NE + e] >> 9], 1);
        }
        __syncthreads();
        if (t < NB) atomicAdd(&gcnt[t], hist[t]);
    }
}

// Phase A: bin edges by dst bucket into dense runs of ebuf.
// Bucket bases derived in-block from gcnt (80-entry scan) - no k_bscan.
__global__ void __launch_bounds__(256)
k_bucket(const int* __restrict__ ei, const int* __restrict__ ea,
         const int* __restrict__ gcnt, int* __restrict__ gbk,
         int2* __restrict__ ebuf) {
    __shared__ int hist[NB];
    __shared__ int sbase[NB];
    __shared__ int sB[128];
    __shared__ int exS[NB];
    int t = threadIdx.x;
    if (t < NB) hist[t] = 0;
    int v0 = 0;
    if (t < 128) { v0 = (t < NB) ? gcnt[t] : 0; sB[t] = v0; }
    __syncthreads();
    for (int d = 1; d < 128; d <<= 1) {
        int add = (t < 128 && t >= d) ? sB[t - d] : 0;
        __syncthreads();
        if (t < 128) sB[t] += add;
        __syncthreads();
    }
    if (t < NB) exS[t] = sB[t] - v0;
    __syncthreads();
    int e0 = blockIdx.x * 1024;
    int rank[4], buck[4], rec[4], dstv[4];
#pragma unroll
    for (int k = 0; k < 4; ++k) {
        int e = e0 + k * 256 + t;
        int src = ei[e];
        int dst = ei[NE + e];
        int a0 = ea[e * 3 + 0], a1 = ea[e * 3 + 1], a2 = ea[e * 3 + 2];
        rec[k] = src | ((a0 | (a1 << 3) | (a2 << 6)) << 16);
        dstv[k] = dst;
        int b = dst >> 9;
        buck[k] = b;
        rank[k] = atomicAdd(&hist[b], 1);
    }
    __syncthreads();
    if (t < NB) sbase[t] = atomicAdd(&gbk[t], hist[t]);
    __syncthreads();
#pragma unroll
    for (int k = 0; k < 4; ++k) {
        int b = buck[k];
        int slot = exS[b] + sbase[b] + rank[k];
        ebuf[slot] = make_int2(rec[k], dstv[k]);
    }
}

// Per-bucket CSR + scatter: one block per bucket (512 nodes, ~8000 edges).
// All heavy atomics LDS-scope; bucket base re-derived in-block from gcnt.
__global__ void __launch_bounds__(256)
k_csr(const int2* __restrict__ ebuf, const int* __restrict__ gcnt,
      int* __restrict__ off, int* __restrict__ epack) {
    __shared__ int cnt[512];
    __shared__ int cur[512];
    __shared__ int sc[256];
    __shared__ int sB[128];
    int b = blockIdx.x, t = threadIdx.x;
    int v0 = 0;
    if (t < 128) { v0 = (t < NB) ? gcnt[t] : 0; sB[t] = v0; }
    cnt[t] = 0; cnt[t + 256] = 0;
    cur[t] = 0; cur[t + 256] = 0;
    __syncthreads();
    for (int d = 1; d < 128; d <<= 1) {
        int add = (t < 128 && t >= d) ? sB[t - d] : 0;
        __syncthreads();
        if (t < 128) sB[t] += add;
        __syncthreads();
    }
    int base = sB[b] - gcnt[b];
    int end = base + gcnt[b];
    __syncthreads();
    for (int i = base + t; i < end; i += 256)
        atomicAdd(&cnt[ebuf[i].y & 511], 1);
    __syncthreads();
    int a = cnt[2 * t], c2 = cnt[2 * t + 1];
    sc[t] = a + c2;
    __syncthreads();
    for (int d = 1; d < 256; d <<= 1) {
        int add = (t >= d) ? sc[t - d] : 0;
        __syncthreads();
        sc[t] += add;
        __syncthreads();
    }
    int ex = sc[t] - (a + c2);
    cnt[2 * t] = ex;
    cnt[2 * t + 1] = ex + a;
    int n0 = (b << 9) + 2 * t;
    if (n0 <= NN) off[n0] = base + ex;
    if (n0 + 1 <= NN) off[n0 + 1] = base + ex + a;
    __syncthreads();
    for (int i = base + t; i < end; i += 256) {
        int2 s = ebuf[i];
        int l = s.y & 511;
        int r = atomicAdd(&cur[l], 1);
        epack[base + cnt[l] + r] = s.x;
    }
}

// Gather v4 (round-10): wave per node; 2 half-waves of 32 lanes, each half
// owns one edge (lane = 4 dims). 16 edges' rows in flight per wave.
__global__ void __launch_bounds__(256)
k_gather(const ushort_t* __restrict__ xin, const uchar_t* __restrict__ x8in,
         const int* __restrict__ off, const int* __restrict__ epack,
         const ushort_t* __restrict__ ebsum16, const float* __restrict__ eps,
         int layer, ushort_t* __restrict__ h16) {
    int t = threadIdx.x;
    int lane = t & 63;
    int half = lane >> 5;
    int q = lane & 31;
    int n = blockIdx.x * 4 + (t >> 6);
    const ushort4* eb4 = (const ushort4*)ebsum16;
    const uint* xu = (const uint*)x8in;
    const ushort4* x4 = (const ushort4*)xin;
    ushort4 xv = x4[(size_t)n * 32 + q];
    float acc[4];
#pragma unroll
    for (int k = 0; k < 4; ++k) acc[k] = 0.f;
    int p = off[n], p1 = off[n + 1];

    int rec[8], recn[8];
    bool have = (p + 16 <= p1);
    if (have) {
#pragma unroll
        for (int j = 0; j < 8; ++j) rec[j] = epack[p + 2 * j + half];
    }
    while (have) {
        int np = p + 16;
        bool nh = (np + 16 <= p1);
        if (nh) {
#pragma unroll
            for (int j = 0; j < 8; ++j) recn[j] = epack[np + 2 * j + half];
        }
        ushort4 vv[8];
        uint ss[8];
#pragma unroll
        for (int j = 0; j < 8; ++j) {
            vv[j] = eb4[(rec[j] >> 16) * 32 + q];
            ss[j] = xu[(size_t)(rec[j] & 0xFFFF) * 32 + q];
        }
#pragma unroll
        for (int j = 0; j < 8; ++j) {
            acc[0] += fmaxf(b2f(vv[j].x) + __builtin_amdgcn_cvt_f32_fp8((int)ss[j], 0), 0.f);
            acc[1] += fmaxf(b2f(vv[j].y) + __builtin_amdgcn_cvt_f32_fp8((int)ss[j], 1), 0.f);
            acc[2] += fmaxf(b2f(vv[j].z) + __builtin_amdgcn_cvt_f32_fp8((int)ss[j], 2), 0.f);
            acc[3] += fmaxf(b2f(vv[j].w) + __builtin_amdgcn_cvt_f32_fp8((int)ss[j], 3), 0.f);
        }
        p = np;
#pragma unroll
        for (int j = 0; j < 8; ++j) rec[j] = recn[j];
        have = nh;
    }
    if (p + 8 <= p1) {
        int r4[4];
#pragma unroll
        for (int j = 0; j < 4; ++j) r4[j] = epack[p + 2 * j + half];
        ushort4 vv[4];
        uint ss[4];
#pragma unroll
        for (int j = 0; j < 4; ++j) {
            vv[j] = eb4[(r4[j] >> 16) * 32 + q];
            ss[j] = xu[(size_t)(r4[j] & 0xFFFF) * 32 + q];
        }
#pragma unroll
        for (int j = 0; j < 4; ++j) {
            acc[0] += fmaxf(b2f(vv[j].x) + __builtin_amdgcn_cvt_f32_fp8((int)ss[j], 0), 0.f);
            acc[1] += fmaxf(b2f(vv[j].y) + __builtin_amdgcn_cvt_f32_fp8((int)ss[j], 1), 0.f);
            acc[2] += fmaxf(b2f(vv[j].z) + __builtin_amdgcn_cvt_f32_fp8((int)ss[j], 2), 0.f);
            acc[3] += fmaxf(b2f(vv[j].w) + __builtin_amdgcn_cvt_f32_fp8((int)ss[j], 3), 0.f);
        }
        p += 8;
    }
    for (; p < p1; p += 2) {
        int eA = epack[p];
        bool hasB = (p + 1 < p1);
        int eB = hasB ? epack[p + 1] : eA;
        int r = half ? eB : eA;
        bool valid = half ? hasB : true;
        ushort4 v = eb4[(r >> 16) * 32 + q];
        uint s = xu[(size_t)(r & 0xFFFF) * 32 + q];
        if (valid) {
            acc[0] += fmaxf(b2f(v.x) + __builtin_amdgcn_cvt_f32_fp8((int)s, 0), 0.f);
            acc[1] += fmaxf(b2f(v.y) + __builtin_amdgcn_cvt_f32_fp8((int)s, 1), 0.f);
            acc[2] += fmaxf(b2f(v.z) + __builtin_amdgcn_cvt_f32_fp8((int)s, 2), 0.f);
            acc[3] += fmaxf(b2f(v.w) + __builtin_amdgcn_cvt_f32_fp8((int)s, 3), 0.f);
        }
    }
#pragma unroll
    for (int k = 0; k < 4; ++k) acc[k] += __shfl_xor(acc[k], 32, 64);
    if (half == 0) {
        float es = 1.f + eps[layer];
        ushort4 o;
        o.x = f2b(acc[0] + es * b2f(xv.x));
        o.y = f2b(acc[1] + es * b2f(xv.y));
        o.z = f2b(acc[2] + es * b2f(xv.z));
        o.w = f2b(acc[3] + es * b2f(xv.w));
        ((ushort4*)h16)[(size_t)n * 32 + q] = o;
    }
}

// Fused MLP on MFMA: 32 nodes per block (round-10 config), 256 threads.
__global__ void __launch_bounds__(256)
k_mlp_mfma(const ushort_t* __restrict__ h16, const ushort_t* __restrict__ W1P,
           const ushort_t* __restrict__ W2P, const float* __restrict__ b1,
           const float* __restrict__ g1, const float* __restrict__ bt1,
           const float* __restrict__ m1, const float* __restrict__ v1,
           const float* __restrict__ b2_, const float* __restrict__ gO,
           const float* __restrict__ btO, const float* __restrict__ mO,
           const float* __restrict__ vO, int relu, ushort_t* __restrict__ xout,
           uchar_t* __restrict__ x8out) {
    __shared__ ushort_t aS[32 * 136];   // 32 rows x 128 (pad +8); reused as fp8 stage
    __shared__ ushort_t mid[32 * 264];  // 32 rows x 256 (pad +8)
    int t = threadIdx.x;
    int wave = t >> 6, lane = t & 63;
    int row0 = blockIdx.x * 32;
    int lrow = lane & 15, quad = lane >> 4;

#pragma unroll
    for (int ps = 0; ps < 2; ++ps) {
        int idx = ps * 256 + t;
        int r = idx >> 4, c = (idx & 15) * 8;
        *(short8*)&aS[r * 136 + c] = *(const short8*)&h16[(row0 + r) * DD + c];
    }
    __syncthreads();

    f32x4 acc1[2][4];
#pragma unroll
    for (int rt = 0; rt < 2; ++rt)
#pragma unroll
        for (int i = 0; i < 4; ++i) acc1[rt][i] = (f32x4){0.f, 0.f, 0.f, 0.f};
#pragma unroll
    for (int kk = 0; kk < 4; ++kk) {
        short8 af0 = *(const short8*)&aS[lrow * 136 + kk * 32 + quad * 8];
        short8 af1 = *(const short8*)&aS[(16 + lrow) * 136 + kk * 32 + quad * 8];
#pragma unroll
        for (int i = 0; i < 4; ++i) {
            int nt = wave * 4 + i;
            short8 bf = *(const short8*)&W1P[((nt * 4 + kk) * 64 + lane) * 8];
            acc1[0][i] = __builtin_amdgcn_mfma_f32_16x16x32_bf16(af0, bf, acc1[0][i], 0, 0, 0);
            acc1[1][i] = __builtin_amdgcn_mfma_f32_16x16x32_bf16(af1, bf, acc1[1][i], 0, 0, 0);
        }
    }
    __syncthreads();  // aS reads done; safe to reuse as fp8 stage
#pragma unroll
    for (int i = 0; i < 4; ++i) {
        int col = (wave * 4 + i) * 16 + lrow;
        float s1 = g1[col] * rsqrtf(v1[col] + 1e-5f);
        float sh = bt1[col] - (m1[col] - b1[col]) * s1;
#pragma unroll
        for (int rt = 0; rt < 2; ++rt)
#pragma unroll
            for (int r = 0; r < 4; ++r) {
                int row = rt * 16 + quad * 4 + r;
                float o = acc1[rt][i][r] * s1 + sh;
                mid[row * 264 + col] = f2b(fmaxf(o, 0.f));
            }
    }
    __syncthreads();

    f32x4 acc2[2][2];
#pragma unroll
    for (int rt = 0; rt < 2; ++rt)
#pragma unroll
        for (int i = 0; i < 2; ++i) acc2[rt][i] = (f32x4){0.f, 0.f, 0.f, 0.f};
#pragma unroll
    for (int kk = 0; kk < 8; ++kk) {
        short8 af0 = *(const short8*)&mid[lrow * 264 + kk * 32 + quad * 8];
        short8 af1 = *(const short8*)&mid[(16 + lrow) * 264 + kk * 32 + quad * 8];
#pragma unroll
        for (int i = 0; i < 2; ++i) {
            int nt = wave * 2 + i;
            short8 bf = *(const short8*)&W2P[((nt * 8 + kk) * 64 + lane) * 8];
            acc2[0][i] = __builtin_amdgcn_mfma_f32_16x16x32_bf16(af0, bf, acc2[0][i], 0, 0, 0);
            acc2[1][i] = __builtin_amdgcn_mfma_f32_16x16x32_bf16(af1, bf, acc2[1][i], 0, 0, 0);
        }
    }
    uchar_t* s8 = (uchar_t*)aS;  // 32*128 = 4096 B stage
#pragma unroll
    for (int i = 0; i < 2; ++i) {
        int col = (wave * 2 + i) * 16 + lrow;
        float s = gO[col] * rsqrtf(vO[col] + 1e-5f);
        float sh = btO[col] - (mO[col] - b2_[col]) * s;
#pragma unroll
        for (int rt = 0; rt < 2; ++rt)
#pragma unroll
            for (int r = 0; r < 4; ++r) {
                int row = rt * 16 + quad * 4 + r;
                float o = acc2[rt][i][r] * s + sh;
                if (relu) o = fmaxf(o, 0.f);
                xout[(row0 + row) * DD + col] = f2b(o);
                s8[row * DD + col] = f2p8(o);
            }
    }
    __syncthreads();
    ((int4*)(x8out + (size_t)row0 * DD))[t] = ((const int4*)s8)[t];
}

// Fused pool+head: 256 threads = 4 row-stripes x 64 dim-pairs (ushort2).
__global__ void k_poolhead(const ushort_t* __restrict__ x16,
                           const int* __restrict__ batch,
                           const float* __restrict__ Wp, const float* __restrict__ bp,
                           float* __restrict__ out) {
    int g = blockIdx.x, t = threadIdx.x;  // 256 threads
    int j = t >> 6, l = t & 63;
    int lo = 0, hi = NN;
    while (lo < hi) { int m = (lo + hi) >> 1; if (batch[m] < g) lo = m + 1; else hi = m; }
    int start = lo;
    hi = NN;
    while (lo < hi) { int m = (lo + hi) >> 1; if (batch[m] < g + 1) lo = m + 1; else hi = m; }
    int end = lo;
    const ushort2* x2 = (const ushort2*)x16;
    float sx = 0.f, sy = 0.f;
    for (int n = start + j; n < end; n += 4) {
        ushort2 v = x2[(size_t)n * 64 + l];
        sx += b2f(v.x);
        sy += b2f(v.y);
    }
    __shared__ float pp[4][DD];
    pp[j][2 * l] = sx;
    pp[j][2 * l + 1] = sy;
    __syncthreads();
    __shared__ float pfin[DD];
    if (t < DD) {
        float c = fmaxf((float)(end - start), 1.f);
        pfin[t] = (pp[0][t] + pp[1][t] + pp[2][t] + pp[3][t]) / c;
    }
    __syncthreads();
    if (t < NT) {
        float acc = bp[t];
#pragma unroll 8
        for (int k = 0; k < DD; ++k) acc = fmaf(pfin[k], Wp[k * NT + t], acc);
        out[g * NT + t] = acc;
    }
}

extern "C" void kernel_launch(void* const* d_in, const int* in_sizes, int n_in,
                              void* d_out, int out_size, void* d_ws, size_t ws_size,
                              hipStream_t stream) {
    const int* x_atom = (const int*)d_in[0];
    const int* edge_index = (const int*)d_in[1];
    const int* edge_attr = (const int*)d_in[2];
    const int* batch = (const int*)d_in[3];
    const float* atom_emb = (const float*)d_in[4];
    const float* bond_emb = (const float*)d_in[5];
    const float* eps = (const float*)d_in[6];
    const float* W1 = (const float*)d_in[7];
    const float* b1 = (const float*)d_in[8];
    const float* g1 = (const float*)d_in[9];
    const float* bt1 = (const float*)d_in[10];
    const float* m1 = (const float*)d_in[11];
    const float* v1 = (const float*)d_in[12];
    const float* W2 = (const float*)d_in[13];
    const float* b2 = (const float*)d_in[14];
    const float* gO = (const float*)d_in[15];
    const float* btO = (const float*)d_in[16];
    const float* mO = (const float*)d_in[17];
    const float* vO = (const float*)d_in[18];
    const float* Wp = (const float*)d_in[19];
    const float* bp = (const float*)d_in[20];

    ushort_t* x16a = (ushort_t*)d_ws;        // N*D bf16
    ushort_t* x16b = x16a + NN * DD;         // N*D bf16
    ushort_t* h16 = x16b + NN * DD;          // N*D bf16
    ushort_t* W1P = h16 + NN * DD;           // NL*32768 bf16
    ushort_t* W2P = W1P + NL * 32768;        // NL*32768 bf16
    ushort_t* ebsum16 = W2P + NL * 32768;    // NL*512*128 bf16
    uchar_t* x8a = (uchar_t*)(ebsum16 + NL * 65536);  // N*D fp8
    uchar_t* x8b = x8a + NN * DD;            // N*D fp8
    int* off = (int*)(x8b + NN * DD);        // 40064
    int* gcnt = off + 40064;                 // 80 (bucket counts)
    int* gbk = gcnt + 80;                    // 80 (bucket cursors)
    int* epack = gbk + 80;                   // NE int (packed src|code<<16)
    int2* ebuf = (int2*)(epack + NE);        // NE int2

    hipMemsetAsync(gcnt, 0, 160 * sizeof(int), stream);

    k_setup<<<4405, 256, 0, stream>>>(W1, W2, bond_emb, x_atom, atom_emb,
                                      edge_index, W1P, W2P, ebsum16, x16a, x8a, gcnt);
    k_bucket<<<NE / 1024, 256, 0, stream>>>(edge_index, edge_attr, gcnt, gbk, ebuf);
    k_csr<<<NB, 256, 0, stream>>>(ebuf, gcnt, off, epack);

    for (int i = 0; i < NL; ++i) {
        ushort_t* xin = (i & 1) ? x16b : x16a;
        ushort_t* xout = (i & 1) ? x16a : x16b;
        uchar_t* x8in = (i & 1) ? x8b : x8a;
        uchar_t* x8out = (i & 1) ? x8a : x8b;
        k_gather<<<NN / 4, 256, 0, stream>>>(xin, x8in, off, epack,
                                             ebsum16 + i * 65536, eps, i, h16);
        k_mlp_mfma<<<NN / 32, 256, 0, stream>>>(
            h16, W1P + (size_t)i * 32768, W2P + (size_t)i * 32768, b1 + i * 256,
            g1 + i * 256, bt1 + i * 256, m1 + i * 256, v1 + i * 256, b2 + i * DD,
            gO + i * DD, btO + i * DD, mO + i * DD, vO + i * DD,
            (i < NL - 1) ? 1 : 0, xout, x8out);
    }
    k_poolhead<<<NG, 256, 0, stream>>>(x16b, batch, Wp, bp, (float*)d_out);
}